// Round 11
// baseline (161.401 us; speedup 1.0000x reference)
//
#include <hip/hip_runtime.h>
#include <hip/hip_bf16.h>
#include <stdint.h>

typedef unsigned short u16;
typedef unsigned int u32;
typedef unsigned long long u64;
typedef float f32x4 __attribute__((ext_vector_type(4)));
typedef float f32x16 __attribute__((ext_vector_type(16)));
typedef short bf16x8 __attribute__((ext_vector_type(8)));
typedef u32 u32x4 __attribute__((ext_vector_type(4)));

#define MFMA(a, b, c) __builtin_amdgcn_mfma_f32_16x16x32_bf16((a), (b), (c), 0, 0, 0)
#define MFMA32(a, b, c) __builtin_amdgcn_mfma_f32_32x32x16_bf16((a), (b), (c), 0, 0, 0)

__device__ __forceinline__ void gll16(const void* g, void* lds) {
  __builtin_amdgcn_global_load_lds(
      (const __attribute__((address_space(1))) u32*)(uintptr_t)g,
      (__attribute__((address_space(3))) u32*)(uintptr_t)lds, 16, 0, 0);
}

__device__ __forceinline__ u16 f2b(float f) {
  union { __hip_bfloat16 h; u16 u; } cv;
  cv.h = __float2bfloat16(f);
  return cv.u;
}
__device__ __forceinline__ float b2f(u16 b) {
  union { u32 u; float f; } cv;
  cv.u = (u32)b << 16;
  return cv.f;
}
__device__ __forceinline__ u32 cvtpk(float lo, float hi) {
  u32 r;
  asm("v_cvt_pk_bf16_f32 %0, %1, %2" : "=v"(r) : "v"(lo), "v"(hi));
  return r;
}

// swizzle: conflict-free for both transpose-writes and column-slice reads
__device__ __forceinline__ int sw(int r) { return ((r ^ (r >> 3)) & 7) << 4; }

// ---------------- fp32 -> bf16 elementwise (vectorized) ----------------
__global__ __launch_bounds__(256) void k_cvt(const float* __restrict__ in,
                                             u16* __restrict__ out, int n4) {
  int i = blockIdx.x * 256 + threadIdx.x;
  if (i >= n4) return;
  const float4 v = reinterpret_cast<const float4*>(in)[i];
  u32 lo = (u32)f2b(v.x) | ((u32)f2b(v.y) << 16);
  u32 hi = (u32)f2b(v.z) | ((u32)f2b(v.w) << 16);
  reinterpret_cast<uint2*>(out)[i] = make_uint2(lo, hi);
}

// ---------------- fp32 in[R][C] -> bf16 out[C][R] (LDS tiled transpose) ----
__global__ __launch_bounds__(256) void k_trcvt(const float* __restrict__ in,
                                               u16* __restrict__ out, int R, int C) {
  __shared__ float tile[64][65];
  const int tid = threadIdx.x;
  const int r0 = blockIdx.y * 64, c0 = blockIdx.x * 64;
  const int tr = tid >> 4;
  const int tc4 = (tid & 15) * 4;
#pragma unroll
  for (int i = 0; i < 4; ++i) {
    const float4 v = *reinterpret_cast<const float4*>(
        &in[(size_t)(r0 + i * 16 + tr) * C + c0 + tc4]);
    tile[i * 16 + tr][tc4 + 0] = v.x;
    tile[i * 16 + tr][tc4 + 1] = v.y;
    tile[i * 16 + tr][tc4 + 2] = v.z;
    tile[i * 16 + tr][tc4 + 3] = v.w;
  }
  __syncthreads();
#pragma unroll
  for (int i = 0; i < 4; ++i) {
    const int c = i * 16 + tr;
    const int r4 = tc4;
    u32 lo = (u32)f2b(tile[r4 + 0][c]) | ((u32)f2b(tile[r4 + 1][c]) << 16);
    u32 hi = (u32)f2b(tile[r4 + 2][c]) | ((u32)f2b(tile[r4 + 3][c]) << 16);
    *reinterpret_cast<uint2*>(&out[(size_t)(c0 + c) * R + r0 + r4]) =
        make_uint2(lo, hi);
  }
}

// ---------------- bf16 GEMM, m97 structure: C = A @ Bt^T (GEMM2) ---------
template <int F32OUT>
__global__ __launch_bounds__(256) void k_gemm(const u16* __restrict__ A,
                                              const u16* __restrict__ Bt,
                                              void* __restrict__ Cout,
                                              int M, int N, int K) {
  __shared__ u16 As[128 * 32];
  __shared__ u16 Bs[128 * 32];
  const int tid = threadIdx.x;
  const int lane = tid & 63;
  const int w = tid >> 6;
  const int wm = w >> 1, wn = w & 1;
  const int l15 = lane & 15, lg = lane >> 4;
  const int brow = blockIdx.y * 128;
  const int bcol = blockIdx.x * 128;

  f32x4 acc[4][4] = {};

  const int r0 = tid >> 2;
  const int k8 = (tid & 3) * 8;
  const u16* Ag0 = A + (size_t)(brow + r0) * K + k8;
  const u16* Ag1 = A + (size_t)(brow + 64 + r0) * K + k8;
  const u16* Bg0 = Bt + (size_t)(bcol + r0) * K + k8;
  const u16* Bg1 = Bt + (size_t)(bcol + 64 + r0) * K + k8;
  u16* Asl0 = As + tid * 8;
  u16* Asl1 = As + 2048 + tid * 8;
  u16* Bsl0 = Bs + tid * 8;
  u16* Bsl1 = Bs + 2048 + tid * 8;

  for (int k0 = 0; k0 < K; k0 += 32) {
    gll16(Ag0 + k0, Asl0);
    gll16(Ag1 + k0, Asl1);
    gll16(Bg0 + k0, Bsl0);
    gll16(Bg1 + k0, Bsl1);
    __syncthreads();
    bf16x8 a[4], b[4];
#pragma unroll
    for (int m = 0; m < 4; ++m)
      a[m] = *(const bf16x8*)&As[(wm * 64 + m * 16 + l15) * 32 + lg * 8];
#pragma unroll
    for (int n = 0; n < 4; ++n)
      b[n] = *(const bf16x8*)&Bs[(wn * 64 + n * 16 + l15) * 32 + lg * 8];
#pragma unroll
    for (int m = 0; m < 4; ++m)
#pragma unroll
      for (int n = 0; n < 4; ++n)
        acc[m][n] = MFMA(a[m], b[n], acc[m][n]);
    __syncthreads();
  }

#pragma unroll
  for (int m = 0; m < 4; ++m) {
    const int row = brow + wm * 64 + m * 16 + lg * 4;
#pragma unroll
    for (int n = 0; n < 4; ++n) {
      const int col = bcol + wn * 64 + n * 16 + l15;
#pragma unroll
      for (int r = 0; r < 4; ++r) {
        const float v = acc[m][n][r];
        if (F32OUT)
          ((float*)Cout)[(size_t)(row + r) * N + col] = v;
        else
          ((u16*)Cout)[(size_t)(row + r) * N + col] = f2b(v);
      }
    }
  }
}

// ---------------- GEMM1: qkv = x @ w_attn, 4096x3072x1024 ----------------
// 256x192 tile, 512 thr / 8 waves, BK=64, dbuf LDS, 4-phase interleave.
__global__ __launch_bounds__(512, 1) void k_gemm1(const u16* __restrict__ A,
                                                  const u16* __restrict__ Bt,
                                                  u16* __restrict__ C) {
  __shared__ u16 As[2][256 * 64];  // 32KB each, rows 128B, sw-swizzled
  __shared__ u16 Bs[2][192 * 64];  // 24KB each
  const int tid = threadIdx.x;
  const int lane = tid & 63;
  const int w = tid >> 6;
  const int wm = w >> 2, wn = w & 3;
  const int l15 = lane & 15, lg = lane >> 4;

  const int bid = blockIdx.x;                 // 0..255
  const int lin = (bid & 7) * 32 + (bid >> 3);  // XCD-chunked
  const int bm = lin >> 4, bn = lin & 15;
  const size_t brow = (size_t)bm * 256, bcol = (size_t)bn * 192;

  const int sr = tid >> 3;                  // 0..63
  const int scb = (tid & 7) * 16;           // bytes
  const int gcol = (scb ^ sw(sr)) >> 1;     // u16 units
  const u16* Ag[4];
#pragma unroll
  for (int i = 0; i < 4; ++i) Ag[i] = A + (brow + i * 64 + sr) * 1024 + gcol;
  const u16* Bg[3];
#pragma unroll
  for (int i = 0; i < 3; ++i) Bg[i] = Bt + (bcol + i * 64 + sr) * 1024 + gcol;

  f32x4 acc[8][3] = {};

#pragma unroll
  for (int i = 0; i < 4; ++i) gll16(Ag[i], (char*)As[0] + i * 8192 + tid * 16);
#pragma unroll
  for (int i = 0; i < 3; ++i) gll16(Bg[i], (char*)Bs[0] + i * 8192 + tid * 16);
  asm volatile("s_waitcnt vmcnt(0) lgkmcnt(0)" ::: "memory");
  __builtin_amdgcn_s_barrier();
  __builtin_amdgcn_sched_barrier(0);

  for (int kt = 0; kt < 16; ++kt) {
    const int cur = kt & 1;
    const char* as = (const char*)As[cur];
    const char* bs = (const char*)Bs[cur];
    char* asn = (char*)As[cur ^ 1];
    char* bsn = (char*)Bs[cur ^ 1];
    const bool more = (kt + 1 < 16);
    const int ko = (kt + 1) * 64;

    bf16x8 bfr[3][2];
#pragma unroll
    for (int n = 0; n < 3; ++n) {
      const int row = wn * 48 + n * 16 + l15;
#pragma unroll
      for (int kh = 0; kh < 2; ++kh)
        bfr[n][kh] = *(const bf16x8*)(bs + row * 128 +
                                      ((kh * 64 + lg * 16) ^ sw(row)));
    }
#define GPHASE(MB, STAGE_A, STAGE_B, LAST)                                    \
    {                                                                         \
      bf16x8 af[2][2];                                                        \
      _Pragma("unroll")                                                       \
      for (int mm = 0; mm < 2; ++mm) {                                        \
        const int row = wm * 128 + (MB + mm) * 16 + l15;                      \
        _Pragma("unroll")                                                     \
        for (int kh = 0; kh < 2; ++kh)                                        \
          af[mm][kh] = *(const bf16x8*)(as + row * 128 +                      \
                                        ((kh * 64 + lg * 16) ^ sw(row)));     \
      }                                                                       \
      if (STAGE_A && more) {                                                  \
        _Pragma("unroll")                                                     \
        for (int i = 0; i < 4; ++i)                                           \
          gll16(Ag[i] + ko, asn + i * 8192 + tid * 16);                       \
      }                                                                       \
      if (STAGE_B && more) {                                                  \
        _Pragma("unroll")                                                     \
        for (int i = 0; i < 3; ++i)                                           \
          gll16(Bg[i] + ko, bsn + i * 8192 + tid * 16);                       \
      }                                                                       \
      __builtin_amdgcn_s_setprio(1);                                          \
      _Pragma("unroll")                                                       \
      for (int mm = 0; mm < 2; ++mm)                                          \
        _Pragma("unroll")                                                     \
        for (int n = 0; n < 3; ++n) {                                         \
          acc[MB + mm][n] = MFMA(af[mm][0], bfr[n][0], acc[MB + mm][n]);      \
          acc[MB + mm][n] = MFMA(af[mm][1], bfr[n][1], acc[MB + mm][n]);      \
        }                                                                     \
      __builtin_amdgcn_s_setprio(0);                                          \
      if (LAST) {                                                             \
        asm volatile("s_waitcnt vmcnt(0) lgkmcnt(0)" ::: "memory");           \
      }                                                                       \
      __builtin_amdgcn_s_barrier();                                           \
    }
    GPHASE(0, 1, 0, 0)
    GPHASE(2, 0, 1, 0)
    GPHASE(4, 0, 0, 0)
    GPHASE(6, 0, 0, 1)
#undef GPHASE
    __builtin_amdgcn_sched_barrier(0);
  }

#pragma unroll
  for (int m = 0; m < 8; ++m) {
    const size_t row = brow + wm * 128 + m * 16 + lg * 4;
#pragma unroll
    for (int n = 0; n < 3; ++n) {
      const size_t col = bcol + wn * 48 + n * 16 + l15;
#pragma unroll
      for (int r = 0; r < 4; ++r)
        C[(row + r) * 3072 + col] = f2b(acc[m][n][r]);
    }
  }
}

// ---------------- fused causal flash attention (v10) ---------------------
// v9 compute structure, 512 SINGLE-q-tile blocks, 2 blocks/CU (41KB LDS via
// aliasing the O-merge buffer onto the dead K/V buffers post-drain).
// Desynced co-resident blocks hide each other's barrier stalls; XCD-aware
// mapping pairs q-tiles (k, 15-k) onto the same CU -> ~uniform 34 steps/CU.
__global__ __launch_bounds__(512, 4) void k_attn(const u16* __restrict__ qkv,
                                                 u16* __restrict__ y) {
  __shared__ char smem[40960];
  // live during main loop:
  char* KlB = smem;                 // 3 x 8192  [t][d] sw(t)
  char* VtB = smem + 24576;         // 2 x 8192  [d][t] sw(d)
  // live during epilogue only (aliases KlB/VtB after full drain):
  float (*Om)[64][33] = (float (*)[64][33])smem;          // 4x64x33x4 = 33792
  float (*Lm)[2][32] = (float (*)[2][32])(smem + 33792);  // 1024

  const int tid = threadIdx.x;
  const int lane = tid & 63;
  const int w = tid >> 6;
  const int qsub = w & 3, tsub = w >> 2;
  const int l31 = lane & 31, hi = lane >> 5;

  // mapping: bid -> xcd | j(0..63). Blocks j and j+32 land on the same CU
  // (in-order capacity-2 assignment): give them q-tiles k and 15-k.
  const int bid = blockIdx.x;          // 0..511
  const int xcd = bid & 7;
  const int j = bid >> 3;              // 0..63
  const int half = j >> 5;             // 0 | 1
  const int jj = j & 31;
  const int hl = half * 2 + (jj >> 4); // head-local 0..3
  const int qi0 = jj & 15;
  const int qi = half ? (15 - qi0) : qi0;
  const int bh = xcd * 4 + hl;
  const int b = bh >> 4, h = bh & 15;

  const u16* Qg = qkv + (size_t)(b * 2048) * 3072 + h * 64;
  const u16* Kg = Qg + 1024;
  const u16* Vg = Qg + 2048;

  const int srow = tid >> 3;
  const int scol = (((tid & 7) * 16) ^ sw(srow)) >> 1;
  const bool vstage = (tid < 256);
  const int t2 = (tid & 255) >> 3;
  const int d8 = (tid & 7) * 8;

  bf16x8 vone;
#pragma unroll
  for (int jn = 0; jn < 8; ++jn) vone[jn] = (short)0x3F80;

  const int trow = tsub * 32 + l31;
  int koff[4];
#pragma unroll
  for (int ks = 0; ks < 4; ++ks)
    koff[ks] = trow * 128 + (((ks * 16 + hi * 8) * 2) ^ sw(trow));
  int voff[2][2];
#pragma unroll
  for (int db = 0; db < 2; ++db) {
    const int dl = db * 32 + l31;
#pragma unroll
    for (int ks = 0; ks < 2; ++ks)
      voff[db][ks] = dl * 128 + (((tsub * 32 + ks * 16 + hi * 8) * 2) ^ sw(dl));
  }

  const int nt = 2 * (qi + 1);
  const int qb = qi * 128;
  const int qrow = qb + qsub * 32 + l31;

  bf16x8 aq[4];
#pragma unroll
  for (int ks = 0; ks < 4; ++ks) {
    bf16x8 v = *(const bf16x8*)&Qg[(size_t)qrow * 3072 + ks * 16 + hi * 8];
#pragma unroll
    for (int jn = 0; jn < 8; ++jn)
      v[jn] = (short)f2b(b2f((u16)v[jn]) * 0.18033688011112042f);
    aq[ks] = v;
  }

  f32x16 acc0 = {}, acc1 = {}, accl = {};

  bf16x8 va0, va1;
  {
    bf16x8 v00, v01;
    if (vstage) {
      v00 = *(const bf16x8*)&Vg[(size_t)(2 * t2) * 3072 + d8];
      v01 = *(const bf16x8*)&Vg[(size_t)(2 * t2 + 1) * 3072 + d8];
      va0 = *(const bf16x8*)&Vg[(size_t)(64 + 2 * t2) * 3072 + d8];
      va1 = *(const bf16x8*)&Vg[(size_t)(64 + 2 * t2 + 1) * 3072 + d8];
    }
    gll16(Kg + (size_t)srow * 3072 + scol, (u16*)KlB + tid * 8);
    gll16(Kg + (size_t)(64 + srow) * 3072 + scol, (u16*)(KlB + 8192) + tid * 8);
    if (vstage) {
#pragma unroll
      for (int jn = 0; jn < 8; ++jn) {
        const int d = d8 + jn;
        const u32 val = (u32)(u16)v00[jn] | ((u32)(u16)v01[jn] << 16);
        *(u32*)(VtB + ((d * 128 + t2 * 4) ^ sw(d))) = val;
      }
    }
  }
  asm volatile("s_waitcnt vmcnt(1) lgkmcnt(0)" ::: "memory");
  __builtin_amdgcn_s_barrier();
  __builtin_amdgcn_sched_barrier(0);

  const char* kR = KlB;
  const char* kN = KlB + 8192;
  char* kN2 = KlB + 16384;
  const char* vR = VtB;
  char* vW = VtB + 8192;

  for (int t = 0; t < nt; ++t) {
    const int tf = (t + 2 < 31 ? t + 2 : 31);
    bf16x8 vf0, vf1;
    if (vstage) {
      vf0 = *(const bf16x8*)&Vg[(size_t)(tf * 64 + 2 * t2) * 3072 + d8];
      vf1 = *(const bf16x8*)&Vg[(size_t)(tf * 64 + 2 * t2 + 1) * 3072 + d8];
    }
    gll16(Kg + (size_t)(tf * 64 + srow) * 3072 + scol, (u16*)kN2 + tid * 8);

    f32x16 s = {};
#pragma unroll
    for (int ks = 0; ks < 4; ++ks) {
      const bf16x8 kf = *(const bf16x8*)(kR + koff[ks]);
      s = MFMA32(kf, aq[ks], s);
    }

    float p[16];
    if (t >= nt - 2) {
#pragma unroll
      for (int r = 0; r < 16; ++r) {
        const int kkg = t * 64 + tsub * 32 + (r & 3) + 8 * (r >> 2) + 4 * hi;
        p[r] = exp2f(kkg > qrow ? -1e30f : s[r]);
      }
    } else {
#pragma unroll
      for (int r = 0; r < 16; ++r) p[r] = exp2f(s[r]);
    }

    const u32 X0 = cvtpk(p[0], p[1]),   X1 = cvtpk(p[2], p[3]);
    const u32 X2 = cvtpk(p[4], p[5]),   X3 = cvtpk(p[6], p[7]);
    const u32 X4 = cvtpk(p[8], p[9]),   X5 = cvtpk(p[10], p[11]);
    const u32 X6 = cvtpk(p[12], p[13]), X7 = cvtpk(p[14], p[15]);
    const u32 sx0 = (u32)__shfl_xor((int)X0, 32);
    const u32 sx1 = (u32)__shfl_xor((int)X1, 32);
    const u32 sx2 = (u32)__shfl_xor((int)X2, 32);
    const u32 sx3 = (u32)__shfl_xor((int)X3, 32);
    const u32 sx4 = (u32)__shfl_xor((int)X4, 32);
    const u32 sx5 = (u32)__shfl_xor((int)X5, 32);
    const u32 sx6 = (u32)__shfl_xor((int)X6, 32);
    const u32 sx7 = (u32)__shfl_xor((int)X7, 32);
    union { u32x4 u; bf16x8 h; } c0, c1;
    c0.u[0] = hi ? sx2 : X0;
    c0.u[1] = hi ? sx3 : X1;
    c0.u[2] = hi ? X2 : sx0;
    c0.u[3] = hi ? X3 : sx1;
    c1.u[0] = hi ? sx6 : X4;
    c1.u[1] = hi ? sx7 : X5;
    c1.u[2] = hi ? X6 : sx4;
    c1.u[3] = hi ? X7 : sx5;
    const bf16x8 pb0 = c0.h, pb1 = c1.h;

    accl = MFMA32(vone, pb0, accl);
    accl = MFMA32(vone, pb1, accl);
    const bf16x8 vb00 = *(const bf16x8*)(vR + voff[0][0]);
    const bf16x8 vb01 = *(const bf16x8*)(vR + voff[0][1]);
    const bf16x8 vb10 = *(const bf16x8*)(vR + voff[1][0]);
    const bf16x8 vb11 = *(const bf16x8*)(vR + voff[1][1]);
    acc0 = MFMA32(vb00, pb0, acc0);
    acc0 = MFMA32(vb01, pb1, acc0);
    acc1 = MFMA32(vb10, pb0, acc1);
    acc1 = MFMA32(vb11, pb1, acc1);

    if (vstage && t < nt - 1) {
#pragma unroll
      for (int jn = 0; jn < 8; ++jn) {
        const int d = d8 + jn;
        const u32 val = (u32)(u16)va0[jn] | ((u32)(u16)va1[jn] << 16);
        *(u32*)(vW + ((d * 128 + t2 * 4) ^ sw(d))) = val;
      }
    }
    va0 = vf0; va1 = vf1;
    const char* kt_ = kR; kR = kN; kN = kN2; kN2 = (char*)kt_;
    char* vt_ = (char*)vR; vR = vW; vW = vt_;

    asm volatile("s_waitcnt vmcnt(1) lgkmcnt(0)" ::: "memory");
    __builtin_amdgcn_s_barrier();
    __builtin_amdgcn_sched_barrier(0);
  }

  // full drain: K/V buffers (incl. clamped junk prefetches) are now dead;
  // Om/Lm may alias them.
  asm volatile("s_waitcnt vmcnt(0) lgkmcnt(0)" ::: "memory");
  __builtin_amdgcn_s_barrier();
  __builtin_amdgcn_sched_barrier(0);

  if (tsub == 1) {
#pragma unroll
    for (int r = 0; r < 16; ++r) {
      const int d = (r & 3) + 8 * (r >> 2) + 4 * hi;
      Om[qsub][d][l31] = acc0[r];
      Om[qsub][32 + d][l31] = acc1[r];
    }
    Lm[qsub][1][l31] = accl[0];
  } else {
    Lm[qsub][0][l31] = accl[0];
  }
  __syncthreads();
  if (tsub == 0) {
    const float linv = 1.0f / (Lm[qsub][0][l31] + Lm[qsub][1][l31]);
#pragma unroll
    for (int r = 0; r < 16; ++r) {
      const int d = (r & 3) + 8 * (r >> 2) + 4 * hi;
      Om[qsub][d][l31] = (acc0[r] + Om[qsub][d][l31]) * linv;
      Om[qsub][32 + d][l31] = (acc1[r] + Om[qsub][32 + d][l31]) * linv;
    }
  }
  __syncthreads();
  {
    const int qloc = tid >> 2;
    const int dgr = (tid & 3) * 16;
    const size_t yo = (size_t)(b * 2048 + qb + qloc) * 1024 + h * 64 + dgr;
    u32 o[8];
#pragma unroll
    for (int jn = 0; jn < 8; ++jn)
      o[jn] = cvtpk(Om[qloc >> 5][dgr + 2 * jn][qloc & 31],
                    Om[qloc >> 5][dgr + 2 * jn + 1][qloc & 31]);
    u32x4 s0 = {o[0], o[1], o[2], o[3]};
    u32x4 s1 = {o[4], o[5], o[6], o[7]};
    *(u32x4*)&y[yo] = s0;
    *(u32x4*)&y[yo + 8] = s1;
  }
}

// ---------------- host launch ----------------
extern "C" void kernel_launch(void* const* d_in, const int* in_sizes, int n_in,
                              void* d_out, int out_size, void* d_ws, size_t ws_size,
                              hipStream_t stream) {
  const float* x  = (const float*)d_in[0];   // [2,2048,1024]
  const float* wa = (const float*)d_in[1];   // [1024,3072]
  const float* wp = (const float*)d_in[2];   // [1024,1024]
  float* out = (float*)d_out;                // [2,2048,1024] fp32

  u16* xb  = (u16*)d_ws;                 // [4096][1024] bf16
  u16* wat = xb + (size_t)4096 * 1024;   // [3072][1024] bf16 (w_attn^T)
  u16* wpt = wat + (size_t)3072 * 1024;  // [1024][1024] bf16 (w_proj^T)
  u16* qkv = wpt + (size_t)1024 * 1024;  // [4096][3072] bf16
  u16* yb  = qkv + (size_t)4096 * 3072;  // [4096][1024] bf16

  k_cvt<<<4096, 256, 0, stream>>>(x, xb, 4096 * 1024 / 4);
  k_trcvt<<<dim3(3072 / 64, 1024 / 64), 256, 0, stream>>>(wa, wat, 1024, 3072);
  k_trcvt<<<dim3(1024 / 64, 1024 / 64), 256, 0, stream>>>(wp, wpt, 1024, 1024);

  // qkv = x @ w_attn   (bf16 out) -- 256x192 tile, phase-interleaved
  k_gemm1<<<256, 512, 0, stream>>>(xb, wat, qkv);

  // fused causal attention -> y [4096][1024] bf16
  k_attn<<<512, 512, 0, stream>>>(qkv, yb);

  // out = y @ w_proj   (fp32 out)
  k_gemm<1><<<dim3(1024 / 128, 4096 / 128), 256, 0, stream>>>(yb, wpt, out, 4096, 1024, 1024);
}

// Round 12
// 134.042 us; speedup vs baseline: 1.2041x; 1.2041x over previous
//
#include <hip/hip_runtime.h>
#include <hip/hip_bf16.h>
#include <stdint.h>

typedef unsigned short u16;
typedef unsigned int u32;
typedef unsigned long long u64;
typedef float f32x4 __attribute__((ext_vector_type(4)));
typedef float f32x16 __attribute__((ext_vector_type(16)));
typedef short bf16x8 __attribute__((ext_vector_type(8)));
typedef u32 u32x4 __attribute__((ext_vector_type(4)));

#define MFMA(a, b, c) __builtin_amdgcn_mfma_f32_16x16x32_bf16((a), (b), (c), 0, 0, 0)
#define MFMA32(a, b, c) __builtin_amdgcn_mfma_f32_32x32x16_bf16((a), (b), (c), 0, 0, 0)

__device__ __forceinline__ void gll16(const void* g, void* lds) {
  __builtin_amdgcn_global_load_lds(
      (const __attribute__((address_space(1))) u32*)(uintptr_t)g,
      (__attribute__((address_space(3))) u32*)(uintptr_t)lds, 16, 0, 0);
}

__device__ __forceinline__ u16 f2b(float f) {
  union { __hip_bfloat16 h; u16 u; } cv;
  cv.h = __float2bfloat16(f);
  return cv.u;
}
__device__ __forceinline__ float b2f(u16 b) {
  union { u32 u; float f; } cv;
  cv.u = (u32)b << 16;
  return cv.f;
}
__device__ __forceinline__ u32 cvtpk(float lo, float hi) {
  u32 r;
  asm("v_cvt_pk_bf16_f32 %0, %1, %2" : "=v"(r) : "v"(lo), "v"(hi));
  return r;
}

// swizzle: conflict-free for both transpose-writes and column-slice reads
__device__ __forceinline__ int sw(int r) { return ((r ^ (r >> 3)) & 7) << 4; }

// ---------------- fp32 -> bf16 elementwise (vectorized) ----------------
__global__ __launch_bounds__(256) void k_cvt(const float* __restrict__ in,
                                             u16* __restrict__ out, int n4) {
  int i = blockIdx.x * 256 + threadIdx.x;
  if (i >= n4) return;
  const float4 v = reinterpret_cast<const float4*>(in)[i];
  u32 lo = (u32)f2b(v.x) | ((u32)f2b(v.y) << 16);
  u32 hi = (u32)f2b(v.z) | ((u32)f2b(v.w) << 16);
  reinterpret_cast<uint2*>(out)[i] = make_uint2(lo, hi);
}

// ---------------- fp32 in[R][C] -> bf16 out[C][R] (LDS tiled transpose) ----
__global__ __launch_bounds__(256) void k_trcvt(const float* __restrict__ in,
                                               u16* __restrict__ out, int R, int C) {
  __shared__ float tile[64][65];
  const int tid = threadIdx.x;
  const int r0 = blockIdx.y * 64, c0 = blockIdx.x * 64;
  const int tr = tid >> 4;
  const int tc4 = (tid & 15) * 4;
#pragma unroll
  for (int i = 0; i < 4; ++i) {
    const float4 v = *reinterpret_cast<const float4*>(
        &in[(size_t)(r0 + i * 16 + tr) * C + c0 + tc4]);
    tile[i * 16 + tr][tc4 + 0] = v.x;
    tile[i * 16 + tr][tc4 + 1] = v.y;
    tile[i * 16 + tr][tc4 + 2] = v.z;
    tile[i * 16 + tr][tc4 + 3] = v.w;
  }
  __syncthreads();
#pragma unroll
  for (int i = 0; i < 4; ++i) {
    const int c = i * 16 + tr;
    const int r4 = tc4;
    u32 lo = (u32)f2b(tile[r4 + 0][c]) | ((u32)f2b(tile[r4 + 1][c]) << 16);
    u32 hi = (u32)f2b(tile[r4 + 2][c]) | ((u32)f2b(tile[r4 + 3][c]) << 16);
    *reinterpret_cast<uint2*>(&out[(size_t)(c0 + c) * R + r0 + r4]) =
        make_uint2(lo, hi);
  }
}

// ---------------- bf16 GEMM, m97 structure: C = A @ Bt^T (GEMM2) ---------
template <int F32OUT>
__global__ __launch_bounds__(256) void k_gemm(const u16* __restrict__ A,
                                              const u16* __restrict__ Bt,
                                              void* __restrict__ Cout,
                                              int M, int N, int K) {
  __shared__ u16 As[128 * 32];
  __shared__ u16 Bs[128 * 32];
  const int tid = threadIdx.x;
  const int lane = tid & 63;
  const int w = tid >> 6;
  const int wm = w >> 1, wn = w & 1;
  const int l15 = lane & 15, lg = lane >> 4;
  const int brow = blockIdx.y * 128;
  const int bcol = blockIdx.x * 128;

  f32x4 acc[4][4] = {};

  const int r0 = tid >> 2;
  const int k8 = (tid & 3) * 8;
  const u16* Ag0 = A + (size_t)(brow + r0) * K + k8;
  const u16* Ag1 = A + (size_t)(brow + 64 + r0) * K + k8;
  const u16* Bg0 = Bt + (size_t)(bcol + r0) * K + k8;
  const u16* Bg1 = Bt + (size_t)(bcol + 64 + r0) * K + k8;
  u16* Asl0 = As + tid * 8;
  u16* Asl1 = As + 2048 + tid * 8;
  u16* Bsl0 = Bs + tid * 8;
  u16* Bsl1 = Bs + 2048 + tid * 8;

  for (int k0 = 0; k0 < K; k0 += 32) {
    gll16(Ag0 + k0, Asl0);
    gll16(Ag1 + k0, Asl1);
    gll16(Bg0 + k0, Bsl0);
    gll16(Bg1 + k0, Bsl1);
    __syncthreads();
    bf16x8 a[4], b[4];
#pragma unroll
    for (int m = 0; m < 4; ++m)
      a[m] = *(const bf16x8*)&As[(wm * 64 + m * 16 + l15) * 32 + lg * 8];
#pragma unroll
    for (int n = 0; n < 4; ++n)
      b[n] = *(const bf16x8*)&Bs[(wn * 64 + n * 16 + l15) * 32 + lg * 8];
#pragma unroll
    for (int m = 0; m < 4; ++m)
#pragma unroll
      for (int n = 0; n < 4; ++n)
        acc[m][n] = MFMA(a[m], b[n], acc[m][n]);
    __syncthreads();
  }

#pragma unroll
  for (int m = 0; m < 4; ++m) {
    const int row = brow + wm * 64 + m * 16 + lg * 4;
#pragma unroll
    for (int n = 0; n < 4; ++n) {
      const int col = bcol + wn * 64 + n * 16 + l15;
#pragma unroll
      for (int r = 0; r < 4; ++r) {
        const float v = acc[m][n][r];
        if (F32OUT)
          ((float*)Cout)[(size_t)(row + r) * N + col] = v;
        else
          ((u16*)Cout)[(size_t)(row + r) * N + col] = f2b(v);
      }
    }
  }
}

// ---------------- GEMM1: qkv = x @ w_attn, 4096x3072x1024 ----------------
// 256x192 tile, 512 thr / 8 waves, BK=64, dbuf LDS, 4-phase interleave.
__global__ __launch_bounds__(512, 1) void k_gemm1(const u16* __restrict__ A,
                                                  const u16* __restrict__ Bt,
                                                  u16* __restrict__ C) {
  __shared__ u16 As[2][256 * 64];  // 32KB each, rows 128B, sw-swizzled
  __shared__ u16 Bs[2][192 * 64];  // 24KB each
  const int tid = threadIdx.x;
  const int lane = tid & 63;
  const int w = tid >> 6;
  const int wm = w >> 2, wn = w & 3;
  const int l15 = lane & 15, lg = lane >> 4;

  const int bid = blockIdx.x;                 // 0..255
  const int lin = (bid & 7) * 32 + (bid >> 3);  // XCD-chunked
  const int bm = lin >> 4, bn = lin & 15;
  const size_t brow = (size_t)bm * 256, bcol = (size_t)bn * 192;

  const int sr = tid >> 3;                  // 0..63
  const int scb = (tid & 7) * 16;           // bytes
  const int gcol = (scb ^ sw(sr)) >> 1;     // u16 units
  const u16* Ag[4];
#pragma unroll
  for (int i = 0; i < 4; ++i) Ag[i] = A + (brow + i * 64 + sr) * 1024 + gcol;
  const u16* Bg[3];
#pragma unroll
  for (int i = 0; i < 3; ++i) Bg[i] = Bt + (bcol + i * 64 + sr) * 1024 + gcol;

  f32x4 acc[8][3] = {};

#pragma unroll
  for (int i = 0; i < 4; ++i) gll16(Ag[i], (char*)As[0] + i * 8192 + tid * 16);
#pragma unroll
  for (int i = 0; i < 3; ++i) gll16(Bg[i], (char*)Bs[0] + i * 8192 + tid * 16);
  asm volatile("s_waitcnt vmcnt(0) lgkmcnt(0)" ::: "memory");
  __builtin_amdgcn_s_barrier();
  __builtin_amdgcn_sched_barrier(0);

  for (int kt = 0; kt < 16; ++kt) {
    const int cur = kt & 1;
    const char* as = (const char*)As[cur];
    const char* bs = (const char*)Bs[cur];
    char* asn = (char*)As[cur ^ 1];
    char* bsn = (char*)Bs[cur ^ 1];
    const bool more = (kt + 1 < 16);
    const int ko = (kt + 1) * 64;

    bf16x8 bfr[3][2];
#pragma unroll
    for (int n = 0; n < 3; ++n) {
      const int row = wn * 48 + n * 16 + l15;
#pragma unroll
      for (int kh = 0; kh < 2; ++kh)
        bfr[n][kh] = *(const bf16x8*)(bs + row * 128 +
                                      ((kh * 64 + lg * 16) ^ sw(row)));
    }
#define GPHASE(MB, STAGE_A, STAGE_B, LAST)                                    \
    {                                                                         \
      bf16x8 af[2][2];                                                        \
      _Pragma("unroll")                                                       \
      for (int mm = 0; mm < 2; ++mm) {                                        \
        const int row = wm * 128 + (MB + mm) * 16 + l15;                      \
        _Pragma("unroll")                                                     \
        for (int kh = 0; kh < 2; ++kh)                                        \
          af[mm][kh] = *(const bf16x8*)(as + row * 128 +                      \
                                        ((kh * 64 + lg * 16) ^ sw(row)));     \
      }                                                                       \
      if (STAGE_A && more) {                                                  \
        _Pragma("unroll")                                                     \
        for (int i = 0; i < 4; ++i)                                           \
          gll16(Ag[i] + ko, asn + i * 8192 + tid * 16);                       \
      }                                                                       \
      if (STAGE_B && more) {                                                  \
        _Pragma("unroll")                                                     \
        for (int i = 0; i < 3; ++i)                                           \
          gll16(Bg[i] + ko, bsn + i * 8192 + tid * 16);                       \
      }                                                                       \
      __builtin_amdgcn_s_setprio(1);                                          \
      _Pragma("unroll")                                                       \
      for (int mm = 0; mm < 2; ++mm)                                          \
        _Pragma("unroll")                                                     \
        for (int n = 0; n < 3; ++n) {                                         \
          acc[MB + mm][n] = MFMA(af[mm][0], bfr[n][0], acc[MB + mm][n]);      \
          acc[MB + mm][n] = MFMA(af[mm][1], bfr[n][1], acc[MB + mm][n]);      \
        }                                                                     \
      __builtin_amdgcn_s_setprio(0);                                          \
      if (LAST) {                                                             \
        asm volatile("s_waitcnt vmcnt(0) lgkmcnt(0)" ::: "memory");           \
      }                                                                       \
      __builtin_amdgcn_s_barrier();                                           \
    }
    GPHASE(0, 1, 0, 0)
    GPHASE(2, 0, 1, 0)
    GPHASE(4, 0, 0, 0)
    GPHASE(6, 0, 0, 1)
#undef GPHASE
    __builtin_amdgcn_sched_barrier(0);
  }

#pragma unroll
  for (int m = 0; m < 8; ++m) {
    const size_t row = brow + wm * 128 + m * 16 + lg * 4;
#pragma unroll
    for (int n = 0; n < 3; ++n) {
      const size_t col = bcol + wn * 48 + n * 16 + l15;
#pragma unroll
      for (int r = 0; r < 4; ++r)
        C[(row + r) * 3072 + col] = f2b(acc[m][n][r]);
    }
  }
}

// ---------------- fused causal flash attention (v11) ---------------------
// v10 retry without spills: launch_bounds(512,2); l computed via VALU sum
// (frees the 16-reg ones-MFMA accumulator). 512 single-q-tile blocks,
// 41KB LDS (O-merge aliased onto dead K/V buffers) -> 2 blocks/CU natural.
// Same-CU (k,15-k) pairing via in-order capacity-2 assignment.
__global__ __launch_bounds__(512, 2) void k_attn(const u16* __restrict__ qkv,
                                                 u16* __restrict__ y) {
  __shared__ char smem[40960];
  char* KlB = smem;                 // 3 x 8192  [t][d] sw(t)
  char* VtB = smem + 24576;         // 2 x 8192  [d][t] sw(d)
  float (*Om)[64][33] = (float (*)[64][33])smem;          // epilogue alias
  float (*Lm)[2][32] = (float (*)[2][32])(smem + 33792);

  const int tid = threadIdx.x;
  const int lane = tid & 63;
  const int w = tid >> 6;
  const int qsub = w & 3, tsub = w >> 2;
  const int l31 = lane & 31, hi = lane >> 5;

  const int bid = blockIdx.x;          // 0..511
  const int xcd = bid & 7;
  const int j = bid >> 3;              // 0..63
  const int half = j >> 5;             // 0 | 1
  const int jj = j & 31;
  const int hl = half * 2 + (jj >> 4); // head-local 0..3
  const int qi0 = jj & 15;
  const int qi = half ? (15 - qi0) : qi0;
  const int bh = xcd * 4 + hl;
  const int b = bh >> 4, h = bh & 15;

  const u16* Qg = qkv + (size_t)(b * 2048) * 3072 + h * 64;
  const u16* Kg = Qg + 1024;
  const u16* Vg = Qg + 2048;

  const int srow = tid >> 3;
  const int scol = (((tid & 7) * 16) ^ sw(srow)) >> 1;
  const bool vstage = (tid < 256);
  const int t2 = (tid & 255) >> 3;
  const int d8 = (tid & 7) * 8;

  const int trow = tsub * 32 + l31;
  int koff[4];
#pragma unroll
  for (int ks = 0; ks < 4; ++ks)
    koff[ks] = trow * 128 + (((ks * 16 + hi * 8) * 2) ^ sw(trow));
  int voff[2][2];
#pragma unroll
  for (int db = 0; db < 2; ++db) {
    const int dl = db * 32 + l31;
#pragma unroll
    for (int ks = 0; ks < 2; ++ks)
      voff[db][ks] = dl * 128 + (((tsub * 32 + ks * 16 + hi * 8) * 2) ^ sw(dl));
  }

  const int nt = 2 * (qi + 1);
  const int qb = qi * 128;
  const int qrow = qb + qsub * 32 + l31;

  bf16x8 aq[4];
#pragma unroll
  for (int ks = 0; ks < 4; ++ks) {
    bf16x8 v = *(const bf16x8*)&Qg[(size_t)qrow * 3072 + ks * 16 + hi * 8];
#pragma unroll
    for (int jn = 0; jn < 8; ++jn)
      v[jn] = (short)f2b(b2f((u16)v[jn]) * 0.18033688011112042f);
    aq[ks] = v;
  }

  f32x16 acc0 = {}, acc1 = {};
  float laccum = 0.f;

  bf16x8 va0, va1;
  {
    bf16x8 v00, v01;
    if (vstage) {
      v00 = *(const bf16x8*)&Vg[(size_t)(2 * t2) * 3072 + d8];
      v01 = *(const bf16x8*)&Vg[(size_t)(2 * t2 + 1) * 3072 + d8];
      va0 = *(const bf16x8*)&Vg[(size_t)(64 + 2 * t2) * 3072 + d8];
      va1 = *(const bf16x8*)&Vg[(size_t)(64 + 2 * t2 + 1) * 3072 + d8];
    }
    gll16(Kg + (size_t)srow * 3072 + scol, (u16*)KlB + tid * 8);
    gll16(Kg + (size_t)(64 + srow) * 3072 + scol, (u16*)(KlB + 8192) + tid * 8);
    if (vstage) {
#pragma unroll
      for (int jn = 0; jn < 8; ++jn) {
        const int d = d8 + jn;
        const u32 val = (u32)(u16)v00[jn] | ((u32)(u16)v01[jn] << 16);
        *(u32*)(VtB + ((d * 128 + t2 * 4) ^ sw(d))) = val;
      }
    }
  }
  asm volatile("s_waitcnt vmcnt(1) lgkmcnt(0)" ::: "memory");
  __builtin_amdgcn_s_barrier();
  __builtin_amdgcn_sched_barrier(0);

  const char* kR = KlB;
  const char* kN = KlB + 8192;
  char* kN2 = KlB + 16384;
  const char* vR = VtB;
  char* vW = VtB + 8192;

  for (int t = 0; t < nt; ++t) {
    const int tf = (t + 2 < 31 ? t + 2 : 31);
    bf16x8 vf0, vf1;
    if (vstage) {
      vf0 = *(const bf16x8*)&Vg[(size_t)(tf * 64 + 2 * t2) * 3072 + d8];
      vf1 = *(const bf16x8*)&Vg[(size_t)(tf * 64 + 2 * t2 + 1) * 3072 + d8];
    }
    gll16(Kg + (size_t)(tf * 64 + srow) * 3072 + scol, (u16*)kN2 + tid * 8);

    f32x16 s = {};
#pragma unroll
    for (int ks = 0; ks < 4; ++ks) {
      const bf16x8 kf = *(const bf16x8*)(kR + koff[ks]);
      s = MFMA32(kf, aq[ks], s);
    }

    float p[16];
    if (t >= nt - 2) {
#pragma unroll
      for (int r = 0; r < 16; ++r) {
        const int kkg = t * 64 + tsub * 32 + (r & 3) + 8 * (r >> 2) + 4 * hi;
        p[r] = exp2f(kkg > qrow ? -1e30f : s[r]);
      }
    } else {
#pragma unroll
      for (int r = 0; r < 16; ++r) p[r] = exp2f(s[r]);
    }

    // ---- l: VALU tree sum + hi-half exchange (replaces ones-MFMA) ----
    {
      float rs = ((p[0] + p[1]) + (p[2] + p[3])) +
                 ((p[4] + p[5]) + (p[6] + p[7])) +
                 (((p[8] + p[9]) + (p[10] + p[11])) +
                  ((p[12] + p[13]) + (p[14] + p[15])));
      rs += __shfl_xor(rs, 32);
      laccum += rs;
    }

    const u32 X0 = cvtpk(p[0], p[1]),   X1 = cvtpk(p[2], p[3]);
    const u32 X2 = cvtpk(p[4], p[5]),   X3 = cvtpk(p[6], p[7]);
    const u32 X4 = cvtpk(p[8], p[9]),   X5 = cvtpk(p[10], p[11]);
    const u32 X6 = cvtpk(p[12], p[13]), X7 = cvtpk(p[14], p[15]);
    const u32 sx0 = (u32)__shfl_xor((int)X0, 32);
    const u32 sx1 = (u32)__shfl_xor((int)X1, 32);
    const u32 sx2 = (u32)__shfl_xor((int)X2, 32);
    const u32 sx3 = (u32)__shfl_xor((int)X3, 32);
    const u32 sx4 = (u32)__shfl_xor((int)X4, 32);
    const u32 sx5 = (u32)__shfl_xor((int)X5, 32);
    const u32 sx6 = (u32)__shfl_xor((int)X6, 32);
    const u32 sx7 = (u32)__shfl_xor((int)X7, 32);
    union { u32x4 u; bf16x8 h; } c0, c1;
    c0.u[0] = hi ? sx2 : X0;
    c0.u[1] = hi ? sx3 : X1;
    c0.u[2] = hi ? X2 : sx0;
    c0.u[3] = hi ? X3 : sx1;
    c1.u[0] = hi ? sx6 : X4;
    c1.u[1] = hi ? sx7 : X5;
    c1.u[2] = hi ? X6 : sx4;
    c1.u[3] = hi ? X7 : sx5;
    const bf16x8 pb0 = c0.h, pb1 = c1.h;

    const bf16x8 vb00 = *(const bf16x8*)(vR + voff[0][0]);
    const bf16x8 vb01 = *(const bf16x8*)(vR + voff[0][1]);
    const bf16x8 vb10 = *(const bf16x8*)(vR + voff[1][0]);
    const bf16x8 vb11 = *(const bf16x8*)(vR + voff[1][1]);
    acc0 = MFMA32(vb00, pb0, acc0);
    acc0 = MFMA32(vb01, pb1, acc0);
    acc1 = MFMA32(vb10, pb0, acc1);
    acc1 = MFMA32(vb11, pb1, acc1);

    if (vstage && t < nt - 1) {
#pragma unroll
      for (int jn = 0; jn < 8; ++jn) {
        const int d = d8 + jn;
        const u32 val = (u32)(u16)va0[jn] | ((u32)(u16)va1[jn] << 16);
        *(u32*)(vW + ((d * 128 + t2 * 4) ^ sw(d))) = val;
      }
    }
    va0 = vf0; va1 = vf1;
    const char* kt_ = kR; kR = kN; kN = kN2; kN2 = (char*)kt_;
    char* vt_ = (char*)vR; vR = vW; vW = vt_;

    asm volatile("s_waitcnt vmcnt(1) lgkmcnt(0)" ::: "memory");
    __builtin_amdgcn_s_barrier();
    __builtin_amdgcn_sched_barrier(0);
  }

  // full drain: K/V buffers (incl. clamped junk prefetches) now dead;
  // Om/Lm may alias them.
  asm volatile("s_waitcnt vmcnt(0) lgkmcnt(0)" ::: "memory");
  __builtin_amdgcn_s_barrier();
  __builtin_amdgcn_sched_barrier(0);

  if (tsub == 1) {
#pragma unroll
    for (int r = 0; r < 16; ++r) {
      const int d = (r & 3) + 8 * (r >> 2) + 4 * hi;
      Om[qsub][d][l31] = acc0[r];
      Om[qsub][32 + d][l31] = acc1[r];
    }
    Lm[qsub][1][l31] = laccum;
  } else {
    Lm[qsub][0][l31] = laccum;
  }
  __syncthreads();
  if (tsub == 0) {
    const float linv = 1.0f / (Lm[qsub][0][l31] + Lm[qsub][1][l31]);
#pragma unroll
    for (int r = 0; r < 16; ++r) {
      const int d = (r & 3) + 8 * (r >> 2) + 4 * hi;
      Om[qsub][d][l31] = (acc0[r] + Om[qsub][d][l31]) * linv;
      Om[qsub][32 + d][l31] = (acc1[r] + Om[qsub][32 + d][l31]) * linv;
    }
  }
  __syncthreads();
  {
    const int qloc = tid >> 2;
    const int dgr = (tid & 3) * 16;
    const size_t yo = (size_t)(b * 2048 + qb + qloc) * 1024 + h * 64 + dgr;
    u32 o[8];
#pragma unroll
    for (int jn = 0; jn < 8; ++jn)
      o[jn] = cvtpk(Om[qloc >> 5][dgr + 2 * jn][qloc & 31],
                    Om[qloc >> 5][dgr + 2 * jn + 1][qloc & 31]);
    u32x4 s0 = {o[0], o[1], o[2], o[3]};
    u32x4 s1 = {o[4], o[5], o[6], o[7]};
    *(u32x4*)&y[yo] = s0;
    *(u32x4*)&y[yo + 8] = s1;
  }
}

// ---------------- host launch ----------------
extern "C" void kernel_launch(void* const* d_in, const int* in_sizes, int n_in,
                              void* d_out, int out_size, void* d_ws, size_t ws_size,
                              hipStream_t stream) {
  const float* x  = (const float*)d_in[0];   // [2,2048,1024]
  const float* wa = (const float*)d_in[1];   // [1024,3072]
  const float* wp = (const float*)d_in[2];   // [1024,1024]
  float* out = (float*)d_out;                // [2,2048,1024] fp32

  u16* xb  = (u16*)d_ws;                 // [4096][1024] bf16
  u16* wat = xb + (size_t)4096 * 1024;   // [3072][1024] bf16 (w_attn^T)
  u16* wpt = wat + (size_t)3072 * 1024;  // [1024][1024] bf16 (w_proj^T)
  u16* qkv = wpt + (size_t)1024 * 1024;  // [4096][3072] bf16
  u16* yb  = qkv + (size_t)4096 * 3072;  // [4096][1024] bf16

  k_cvt<<<4096, 256, 0, stream>>>(x, xb, 4096 * 1024 / 4);
  k_trcvt<<<dim3(3072 / 64, 1024 / 64), 256, 0, stream>>>(wa, wat, 1024, 3072);
  k_trcvt<<<dim3(1024 / 64, 1024 / 64), 256, 0, stream>>>(wp, wpt, 1024, 1024);

  // qkv = x @ w_attn   (bf16 out) -- 256x192 tile, phase-interleaved
  k_gemm1<<<256, 512, 0, stream>>>(xb, wat, qkv);

  // fused causal attention -> y [4096][1024] bf16
  k_attn<<<512, 512, 0, stream>>>(qkv, yb);

  // out = y @ w_proj   (fp32 out)
  k_gemm<1><<<dim3(1024 / 128, 4096 / 128), 256, 0, stream>>>(yb, wpt, out, 4096, 1024, 1024);
}

// Round 13
// 107.457 us; speedup vs baseline: 1.5020x; 1.2474x over previous
//
#include <hip/hip_runtime.h>
#include <hip/hip_bf16.h>
#include <stdint.h>

typedef unsigned short u16;
typedef unsigned int u32;
typedef unsigned long long u64;
typedef float f32x4 __attribute__((ext_vector_type(4)));
typedef float f32x16 __attribute__((ext_vector_type(16)));
typedef short bf16x8 __attribute__((ext_vector_type(8)));
typedef u32 u32x4 __attribute__((ext_vector_type(4)));

#define MFMA(a, b, c) __builtin_amdgcn_mfma_f32_16x16x32_bf16((a), (b), (c), 0, 0, 0)
#define MFMA32(a, b, c) __builtin_amdgcn_mfma_f32_32x32x16_bf16((a), (b), (c), 0, 0, 0)

__device__ __forceinline__ void gll16(const void* g, void* lds) {
  __builtin_amdgcn_global_load_lds(
      (const __attribute__((address_space(1))) u32*)(uintptr_t)g,
      (__attribute__((address_space(3))) u32*)(uintptr_t)lds, 16, 0, 0);
}

__device__ __forceinline__ u16 f2b(float f) {
  union { __hip_bfloat16 h; u16 u; } cv;
  cv.h = __float2bfloat16(f);
  return cv.u;
}
__device__ __forceinline__ float b2f(u16 b) {
  union { u32 u; float f; } cv;
  cv.u = (u32)b << 16;
  return cv.f;
}
__device__ __forceinline__ u32 cvtpk(float lo, float hi) {
  u32 r;
  asm("v_cvt_pk_bf16_f32 %0, %1, %2" : "=v"(r) : "v"(lo), "v"(hi));
  return r;
}

// swizzle: conflict-free for both transpose-writes and column-slice reads
__device__ __forceinline__ int sw(int r) { return ((r ^ (r >> 3)) & 7) << 4; }

// ---------------- fp32 -> bf16 elementwise (vectorized) ----------------
__global__ __launch_bounds__(256) void k_cvt(const float* __restrict__ in,
                                             u16* __restrict__ out, int n4) {
  int i = blockIdx.x * 256 + threadIdx.x;
  if (i >= n4) return;
  const float4 v = reinterpret_cast<const float4*>(in)[i];
  u32 lo = (u32)f2b(v.x) | ((u32)f2b(v.y) << 16);
  u32 hi = (u32)f2b(v.z) | ((u32)f2b(v.w) << 16);
  reinterpret_cast<uint2*>(out)[i] = make_uint2(lo, hi);
}

// ---------------- fp32 in[R][C] -> bf16 out[C][R] (LDS tiled transpose) ----
__global__ __launch_bounds__(256) void k_trcvt(const float* __restrict__ in,
                                               u16* __restrict__ out, int R, int C) {
  __shared__ float tile[64][65];
  const int tid = threadIdx.x;
  const int r0 = blockIdx.y * 64, c0 = blockIdx.x * 64;
  const int tr = tid >> 4;
  const int tc4 = (tid & 15) * 4;
#pragma unroll
  for (int i = 0; i < 4; ++i) {
    const float4 v = *reinterpret_cast<const float4*>(
        &in[(size_t)(r0 + i * 16 + tr) * C + c0 + tc4]);
    tile[i * 16 + tr][tc4 + 0] = v.x;
    tile[i * 16 + tr][tc4 + 1] = v.y;
    tile[i * 16 + tr][tc4 + 2] = v.z;
    tile[i * 16 + tr][tc4 + 3] = v.w;
  }
  __syncthreads();
#pragma unroll
  for (int i = 0; i < 4; ++i) {
    const int c = i * 16 + tr;
    const int r4 = tc4;
    u32 lo = (u32)f2b(tile[r4 + 0][c]) | ((u32)f2b(tile[r4 + 1][c]) << 16);
    u32 hi = (u32)f2b(tile[r4 + 2][c]) | ((u32)f2b(tile[r4 + 3][c]) << 16);
    *reinterpret_cast<uint2*>(&out[(size_t)(c0 + c) * R + r0 + r4]) =
        make_uint2(lo, hi);
  }
}

// ---------------- GEMM1: qkv = x @ w_attn, 4096x3072x1024 ----------------
// 256x192 tile, 512 thr / 8 waves, BK=64, dbuf LDS, 4-phase interleave.
__global__ __launch_bounds__(512, 1) void k_gemm1(const u16* __restrict__ A,
                                                  const u16* __restrict__ Bt,
                                                  u16* __restrict__ C) {
  __shared__ u16 As[2][256 * 64];  // 32KB each, rows 128B, sw-swizzled
  __shared__ u16 Bs[2][192 * 64];  // 24KB each
  const int tid = threadIdx.x;
  const int lane = tid & 63;
  const int w = tid >> 6;
  const int wm = w >> 2, wn = w & 3;
  const int l15 = lane & 15, lg = lane >> 4;

  const int bid = blockIdx.x;                 // 0..255
  const int lin = (bid & 7) * 32 + (bid >> 3);  // XCD-chunked
  const int bm = lin >> 4, bn = lin & 15;
  const size_t brow = (size_t)bm * 256, bcol = (size_t)bn * 192;

  const int sr = tid >> 3;                  // 0..63
  const int scb = (tid & 7) * 16;           // bytes
  const int gcol = (scb ^ sw(sr)) >> 1;     // u16 units
  const u16* Ag[4];
#pragma unroll
  for (int i = 0; i < 4; ++i) Ag[i] = A + (brow + i * 64 + sr) * 1024 + gcol;
  const u16* Bg[3];
#pragma unroll
  for (int i = 0; i < 3; ++i) Bg[i] = Bt + (bcol + i * 64 + sr) * 1024 + gcol;

  f32x4 acc[8][3] = {};

#pragma unroll
  for (int i = 0; i < 4; ++i) gll16(Ag[i], (char*)As[0] + i * 8192 + tid * 16);
#pragma unroll
  for (int i = 0; i < 3; ++i) gll16(Bg[i], (char*)Bs[0] + i * 8192 + tid * 16);
  asm volatile("s_waitcnt vmcnt(0) lgkmcnt(0)" ::: "memory");
  __builtin_amdgcn_s_barrier();
  __builtin_amdgcn_sched_barrier(0);

  for (int kt = 0; kt < 16; ++kt) {
    const int cur = kt & 1;
    const char* as = (const char*)As[cur];
    const char* bs = (const char*)Bs[cur];
    char* asn = (char*)As[cur ^ 1];
    char* bsn = (char*)Bs[cur ^ 1];
    const bool more = (kt + 1 < 16);
    const int ko = (kt + 1) * 64;

    bf16x8 bfr[3][2];
#pragma unroll
    for (int n = 0; n < 3; ++n) {
      const int row = wn * 48 + n * 16 + l15;
#pragma unroll
      for (int kh = 0; kh < 2; ++kh)
        bfr[n][kh] = *(const bf16x8*)(bs + row * 128 +
                                      ((kh * 64 + lg * 16) ^ sw(row)));
    }
#define GPHASE(MB, STAGE_A, STAGE_B, LAST)                                    \
    {                                                                         \
      bf16x8 af[2][2];                                                        \
      _Pragma("unroll")                                                       \
      for (int mm = 0; mm < 2; ++mm) {                                        \
        const int row = wm * 128 + (MB + mm) * 16 + l15;                      \
        _Pragma("unroll")                                                     \
        for (int kh = 0; kh < 2; ++kh)                                        \
          af[mm][kh] = *(const bf16x8*)(as + row * 128 +                      \
                                        ((kh * 64 + lg * 16) ^ sw(row)));     \
      }                                                                       \
      if (STAGE_A && more) {                                                  \
        _Pragma("unroll")                                                     \
        for (int i = 0; i < 4; ++i)                                           \
          gll16(Ag[i] + ko, asn + i * 8192 + tid * 16);                       \
      }                                                                       \
      if (STAGE_B && more) {                                                  \
        _Pragma("unroll")                                                     \
        for (int i = 0; i < 3; ++i)                                           \
          gll16(Bg[i] + ko, bsn + i * 8192 + tid * 16);                       \
      }                                                                       \
      __builtin_amdgcn_s_setprio(1);                                          \
      _Pragma("unroll")                                                       \
      for (int mm = 0; mm < 2; ++mm)                                          \
        _Pragma("unroll")                                                     \
        for (int n = 0; n < 3; ++n) {                                         \
          acc[MB + mm][n] = MFMA(af[mm][0], bfr[n][0], acc[MB + mm][n]);      \
          acc[MB + mm][n] = MFMA(af[mm][1], bfr[n][1], acc[MB + mm][n]);      \
        }                                                                     \
      __builtin_amdgcn_s_setprio(0);                                          \
      if (LAST) {                                                             \
        asm volatile("s_waitcnt vmcnt(0) lgkmcnt(0)" ::: "memory");           \
      }                                                                       \
      __builtin_amdgcn_s_barrier();                                           \
    }
    GPHASE(0, 1, 0, 0)
    GPHASE(2, 0, 1, 0)
    GPHASE(4, 0, 0, 0)
    GPHASE(6, 0, 0, 1)
#undef GPHASE
    __builtin_amdgcn_sched_barrier(0);
  }

#pragma unroll
  for (int m = 0; m < 8; ++m) {
    const size_t row = brow + wm * 128 + m * 16 + lg * 4;
#pragma unroll
    for (int n = 0; n < 3; ++n) {
      const size_t col = bcol + wn * 48 + n * 16 + l15;
#pragma unroll
      for (int r = 0; r < 4; ++r)
        C[(row + r) * 3072 + col] = f2b(acc[m][n][r]);
    }
  }
}

// ---------------- GEMM2: out = y @ w_proj, 4096x1024x1024, fp32 out ------
// 128x128 tile -> grid 32x8 = 256 blocks = 1/CU. 256 thr / 4 waves (2x2),
// per-wave 64x64. BK=64 dbuf (64KB -> 2 blocks/CU). 4-phase interleave,
// staging in P0 (A) / P1 (B), drain at P3 (~3-phase lead). T2 swizzle.
__global__ __launch_bounds__(256) void k_gemm2(const u16* __restrict__ A,
                                               const u16* __restrict__ Bt,
                                               float* __restrict__ C) {
  __shared__ u16 As[2][128 * 64];  // 16KB each
  __shared__ u16 Bs[2][128 * 64];  // 16KB each
  const int tid = threadIdx.x;
  const int lane = tid & 63;
  const int w = tid >> 6;
  const int wm = w >> 1, wn = w & 1;
  const int l15 = lane & 15, lg = lane >> 4;

  const int bid = blockIdx.x;                  // 0..255
  const int lin = (bid & 7) * 32 + (bid >> 3); // XCD-chunked
  const int bm = lin >> 3, bn = lin & 7;       // 32 x 8
  const size_t brow = (size_t)bm * 128, bcol = (size_t)bn * 128;

  const int sr = tid >> 3;                  // 0..31
  const int scb = (tid & 7) * 16;           // bytes
  const u16* Ag[4];
  const u16* Bg[4];
#pragma unroll
  for (int i = 0; i < 4; ++i) {
    const int row = i * 32 + sr;
    const int gcol = (scb ^ sw(row)) >> 1;
    Ag[i] = A + (brow + row) * 1024 + gcol;
    Bg[i] = Bt + (bcol + row) * 1024 + gcol;
  }

  f32x4 acc[4][4] = {};

#pragma unroll
  for (int i = 0; i < 4; ++i) gll16(Ag[i], (char*)As[0] + i * 4096 + tid * 16);
#pragma unroll
  for (int i = 0; i < 4; ++i) gll16(Bg[i], (char*)Bs[0] + i * 4096 + tid * 16);
  asm volatile("s_waitcnt vmcnt(0) lgkmcnt(0)" ::: "memory");
  __builtin_amdgcn_s_barrier();
  __builtin_amdgcn_sched_barrier(0);

  for (int kt = 0; kt < 16; ++kt) {
    const int cur = kt & 1;
    const char* as = (const char*)As[cur];
    const char* bs = (const char*)Bs[cur];
    char* asn = (char*)As[cur ^ 1];
    char* bsn = (char*)Bs[cur ^ 1];
    const bool more = (kt + 1 < 16);
    const int ko = (kt + 1) * 64;

    bf16x8 bfr[4][2];
#pragma unroll
    for (int n = 0; n < 4; ++n) {
      const int row = wn * 64 + n * 16 + l15;
#pragma unroll
      for (int kh = 0; kh < 2; ++kh)
        bfr[n][kh] = *(const bf16x8*)(bs + row * 128 +
                                      ((kh * 64 + lg * 16) ^ sw(row)));
    }
#define G2PHASE(MB, STAGE_A, STAGE_B, LAST)                                   \
    {                                                                         \
      bf16x8 af[2];                                                           \
      {                                                                       \
        const int row = wm * 64 + (MB) * 16 + l15;                            \
        _Pragma("unroll")                                                     \
        for (int kh = 0; kh < 2; ++kh)                                        \
          af[kh] = *(const bf16x8*)(as + row * 128 +                          \
                                    ((kh * 64 + lg * 16) ^ sw(row)));         \
      }                                                                       \
      if (STAGE_A && more) {                                                  \
        _Pragma("unroll")                                                     \
        for (int i = 0; i < 4; ++i)                                           \
          gll16(Ag[i] + ko, asn + i * 4096 + tid * 16);                       \
      }                                                                       \
      if (STAGE_B && more) {                                                  \
        _Pragma("unroll")                                                     \
        for (int i = 0; i < 4; ++i)                                           \
          gll16(Bg[i] + ko, bsn + i * 4096 + tid * 16);                       \
      }                                                                       \
      __builtin_amdgcn_s_setprio(1);                                          \
      _Pragma("unroll")                                                       \
      for (int n = 0; n < 4; ++n) {                                           \
        acc[MB][n] = MFMA(af[0], bfr[n][0], acc[MB][n]);                      \
        acc[MB][n] = MFMA(af[1], bfr[n][1], acc[MB][n]);                      \
      }                                                                       \
      __builtin_amdgcn_s_setprio(0);                                          \
      if (LAST) {                                                             \
        asm volatile("s_waitcnt vmcnt(0) lgkmcnt(0)" ::: "memory");           \
      }                                                                       \
      __builtin_amdgcn_s_barrier();                                           \
    }
    G2PHASE(0, 1, 0, 0)
    G2PHASE(1, 0, 1, 0)
    G2PHASE(2, 0, 0, 0)
    G2PHASE(3, 0, 0, 1)
#undef G2PHASE
    __builtin_amdgcn_sched_barrier(0);
  }

#pragma unroll
  for (int m = 0; m < 4; ++m) {
    const size_t row = brow + wm * 64 + m * 16 + lg * 4;
#pragma unroll
    for (int n = 0; n < 4; ++n) {
      const size_t col = bcol + wn * 64 + n * 16 + l15;
#pragma unroll
      for (int r = 0; r < 4; ++r)
        C[(row + r) * 1024 + col] = acc[m][n][r];
    }
  }
}

// ---------------- fused causal flash attention (v9 — best known) ---------
// 256 blocks x 512 thr (8 waves = 4 q-subs x 2 t-subs). 128-q tiles paired
// (k,15-k) -> 34 uniform 64-kv steps. 32x32x16 MFMA; swapped QK^T; P stays
// in register (cvt_pk + shfl_xor(32) exchange). Max-free softmax. K staged
// 2-ahead (tri-buffer gll), V reg-staged 1-ahead, counted vmcnt(1).
__global__ __launch_bounds__(512, 1) void k_attn(const u16* __restrict__ qkv,
                                                 u16* __restrict__ y) {
  __shared__ u16 Kl[3][64 * 64];     // [t][d] sw(t)      24KB
  __shared__ u16 Vt[2][64 * 64];     // [d][t] sw(d)      16KB
  __shared__ float Om[4][64][33];    // O merge (padded)  33.8KB
  __shared__ float Lm[4][2][32];     // l partials        1KB
  const int tid = threadIdx.x;
  const int lane = tid & 63;
  const int w = tid >> 6;
  const int qsub = w & 3, tsub = w >> 2;
  const int l31 = lane & 31, hi = lane >> 5;

  const int lin = blockIdx.x;          // 0..255
  const int xcd = lin & 7;
  const int idx = lin >> 3;            // 0..31
  const int bh = xcd * 4 + (idx >> 3); // 0..31
  const int pidx = idx & 7;            // pair index 0..7
  const int b = bh >> 4, h = bh & 15;

  const u16* Qg = qkv + (size_t)(b * 2048) * 3072 + h * 64;
  const u16* Kg = Qg + 1024;
  const u16* Vg = Qg + 2048;

  const int srow = tid >> 3;
  const int scol = (((tid & 7) * 16) ^ sw(srow)) >> 1;
  const bool vstage = (tid < 256);
  const int t2 = (tid & 255) >> 3;
  const int d8 = (tid & 7) * 8;

  bf16x8 vone;
#pragma unroll
  for (int j = 0; j < 8; ++j) vone[j] = (short)0x3F80;

  const int trow = tsub * 32 + l31;
  int koff[4];
#pragma unroll
  for (int ks = 0; ks < 4; ++ks)
    koff[ks] = trow * 128 + (((ks * 16 + hi * 8) * 2) ^ sw(trow));
  int voff[2][2];
#pragma unroll
  for (int db = 0; db < 2; ++db) {
    const int dl = db * 32 + l31;
#pragma unroll
    for (int ks = 0; ks < 2; ++ks)
      voff[db][ks] = dl * 128 + (((tsub * 32 + ks * 16 + hi * 8) * 2) ^ sw(dl));
  }

  for (int pass = 0; pass < 2; ++pass) {
    const int qi = pass ? (15 - pidx) : pidx;
    const int nt = 2 * (qi + 1);
    const int qb = qi * 128;
    const int qrow = qb + qsub * 32 + l31;

    bf16x8 aq[4];
#pragma unroll
    for (int ks = 0; ks < 4; ++ks) {
      bf16x8 v = *(const bf16x8*)&Qg[(size_t)qrow * 3072 + ks * 16 + hi * 8];
#pragma unroll
      for (int j = 0; j < 8; ++j)
        v[j] = (short)f2b(b2f((u16)v[j]) * 0.18033688011112042f);
      aq[ks] = v;
    }

    f32x16 acc0 = {}, acc1 = {}, accl = {};

    bf16x8 va0, va1;
    {
      bf16x8 v00, v01;
      if (vstage) {
        v00 = *(const bf16x8*)&Vg[(size_t)(2 * t2) * 3072 + d8];
        v01 = *(const bf16x8*)&Vg[(size_t)(2 * t2 + 1) * 3072 + d8];
        va0 = *(const bf16x8*)&Vg[(size_t)(64 + 2 * t2) * 3072 + d8];
        va1 = *(const bf16x8*)&Vg[(size_t)(64 + 2 * t2 + 1) * 3072 + d8];
      }
      gll16(Kg + (size_t)srow * 3072 + scol, (u16*)Kl[0] + tid * 8);
      gll16(Kg + (size_t)(64 + srow) * 3072 + scol, (u16*)Kl[1] + tid * 8);
      if (vstage) {
#pragma unroll
        for (int j = 0; j < 8; ++j) {
          const int d = d8 + j;
          const u32 val = (u32)(u16)v00[j] | ((u32)(u16)v01[j] << 16);
          *(u32*)((char*)Vt[0] + ((d * 128 + t2 * 4) ^ sw(d))) = val;
        }
      }
    }
    asm volatile("s_waitcnt vmcnt(1) lgkmcnt(0)" ::: "memory");
    __builtin_amdgcn_s_barrier();
    __builtin_amdgcn_sched_barrier(0);

    const char* kR = (const char*)Kl[0];
    const char* kN = (const char*)Kl[1];
    char* kN2 = (char*)Kl[2];
    const char* vR = (const char*)Vt[0];
    char* vW = (char*)Vt[1];

    for (int t = 0; t < nt; ++t) {
      const int tf = (t + 2 < 31 ? t + 2 : 31);
      bf16x8 vf0, vf1;
      if (vstage) {
        vf0 = *(const bf16x8*)&Vg[(size_t)(tf * 64 + 2 * t2) * 3072 + d8];
        vf1 = *(const bf16x8*)&Vg[(size_t)(tf * 64 + 2 * t2 + 1) * 3072 + d8];
      }
      gll16(Kg + (size_t)(tf * 64 + srow) * 3072 + scol, (u16*)kN2 + tid * 8);

      f32x16 s = {};
#pragma unroll
      for (int ks = 0; ks < 4; ++ks) {
        const bf16x8 kf = *(const bf16x8*)(kR + koff[ks]);
        s = MFMA32(kf, aq[ks], s);
      }

      float p[16];
      if (t >= nt - 2) {
#pragma unroll
        for (int r = 0; r < 16; ++r) {
          const int kkg = t * 64 + tsub * 32 + (r & 3) + 8 * (r >> 2) + 4 * hi;
          p[r] = exp2f(kkg > qrow ? -1e30f : s[r]);
        }
      } else {
#pragma unroll
        for (int r = 0; r < 16; ++r) p[r] = exp2f(s[r]);
      }

      const u32 X0 = cvtpk(p[0], p[1]),   X1 = cvtpk(p[2], p[3]);
      const u32 X2 = cvtpk(p[4], p[5]),   X3 = cvtpk(p[6], p[7]);
      const u32 X4 = cvtpk(p[8], p[9]),   X5 = cvtpk(p[10], p[11]);
      const u32 X6 = cvtpk(p[12], p[13]), X7 = cvtpk(p[14], p[15]);
      const u32 sx0 = (u32)__shfl_xor((int)X0, 32);
      const u32 sx1 = (u32)__shfl_xor((int)X1, 32);
      const u32 sx2 = (u32)__shfl_xor((int)X2, 32);
      const u32 sx3 = (u32)__shfl_xor((int)X3, 32);
      const u32 sx4 = (u32)__shfl_xor((int)X4, 32);
      const u32 sx5 = (u32)__shfl_xor((int)X5, 32);
      const u32 sx6 = (u32)__shfl_xor((int)X6, 32);
      const u32 sx7 = (u32)__shfl_xor((int)X7, 32);
      union { u32x4 u; bf16x8 h; } c0, c1;
      c0.u[0] = hi ? sx2 : X0;
      c0.u[1] = hi ? sx3 : X1;
      c0.u[2] = hi ? X2 : sx0;
      c0.u[3] = hi ? X3 : sx1;
      c1.u[0] = hi ? sx6 : X4;
      c1.u[1] = hi ? sx7 : X5;
      c1.u[2] = hi ? X6 : sx4;
      c1.u[3] = hi ? X7 : sx5;
      const bf16x8 pb0 = c0.h, pb1 = c1.h;

      accl = MFMA32(vone, pb0, accl);
      accl = MFMA32(vone, pb1, accl);
      const bf16x8 vb00 = *(const bf16x8*)(vR + voff[0][0]);
      const bf16x8 vb01 = *(const bf16x8*)(vR + voff[0][1]);
      const bf16x8 vb10 = *(const bf16x8*)(vR + voff[1][0]);
      const bf16x8 vb11 = *(const bf16x8*)(vR + voff[1][1]);
      acc0 = MFMA32(vb00, pb0, acc0);
      acc0 = MFMA32(vb01, pb1, acc0);
      acc1 = MFMA32(vb10, pb0, acc1);
      acc1 = MFMA32(vb11, pb1, acc1);

      if (vstage && t < nt - 1) {
#pragma unroll
        for (int j = 0; j < 8; ++j) {
          const int d = d8 + j;
          const u32 val = (u32)(u16)va0[j] | ((u32)(u16)va1[j] << 16);
          *(u32*)(vW + ((d * 128 + t2 * 4) ^ sw(d))) = val;
        }
      }
      va0 = vf0; va1 = vf1;
      const char* kt = kR; kR = kN; kN = kN2; kN2 = (char*)kt;
      char* vt_ = (char*)vR; vR = vW; vW = vt_;

      asm volatile("s_waitcnt vmcnt(1) lgkmcnt(0)" ::: "memory");
      __builtin_amdgcn_s_barrier();
      __builtin_amdgcn_sched_barrier(0);
    }

    asm volatile("s_waitcnt vmcnt(0) lgkmcnt(0)" ::: "memory");
    __builtin_amdgcn_s_barrier();
    __builtin_amdgcn_sched_barrier(0);

    if (tsub == 1) {
#pragma unroll
      for (int r = 0; r < 16; ++r) {
        const int d = (r & 3) + 8 * (r >> 2) + 4 * hi;
        Om[qsub][d][l31] = acc0[r];
        Om[qsub][32 + d][l31] = acc1[r];
      }
      Lm[qsub][1][l31] = accl[0];
    } else {
      Lm[qsub][0][l31] = accl[0];
    }
    __syncthreads();
    if (tsub == 0) {
      const float linv = 1.0f / (Lm[qsub][0][l31] + Lm[qsub][1][l31]);
#pragma unroll
      for (int r = 0; r < 16; ++r) {
        const int d = (r & 3) + 8 * (r >> 2) + 4 * hi;
        Om[qsub][d][l31] = (acc0[r] + Om[qsub][d][l31]) * linv;
        Om[qsub][32 + d][l31] = (acc1[r] + Om[qsub][32 + d][l31]) * linv;
      }
    }
    __syncthreads();
    {
      const int qloc = tid >> 2;
      const int dgr = (tid & 3) * 16;
      const size_t yo = (size_t)(b * 2048 + qb + qloc) * 1024 + h * 64 + dgr;
      u32 o[8];
#pragma unroll
      for (int jj = 0; jj < 8; ++jj)
        o[jj] = cvtpk(Om[qloc >> 5][dgr + 2 * jj][qloc & 31],
                      Om[qloc >> 5][dgr + 2 * jj + 1][qloc & 31]);
      u32x4 s0 = {o[0], o[1], o[2], o[3]};
      u32x4 s1 = {o[4], o[5], o[6], o[7]};
      *(u32x4*)&y[yo] = s0;
      *(u32x4*)&y[yo + 8] = s1;
    }
    __syncthreads();
  }
}

// ---------------- host launch ----------------
extern "C" void kernel_launch(void* const* d_in, const int* in_sizes, int n_in,
                              void* d_out, int out_size, void* d_ws, size_t ws_size,
                              hipStream_t stream) {
  const float* x  = (const float*)d_in[0];   // [2,2048,1024]
  const float* wa = (const float*)d_in[1];   // [1024,3072]
  const float* wp = (const float*)d_in[2];   // [1024,1024]
  float* out = (float*)d_out;                // [2,2048,1024] fp32

  u16* xb  = (u16*)d_ws;                 // [4096][1024] bf16
  u16* wat = xb + (size_t)4096 * 1024;   // [3072][1024] bf16 (w_attn^T)
  u16* wpt = wat + (size_t)3072 * 1024;  // [1024][1024] bf16 (w_proj^T)
  u16* qkv = wpt + (size_t)1024 * 1024;  // [4096][3072] bf16
  u16* yb  = qkv + (size_t)4096 * 3072;  // [4096][1024] bf16

  k_cvt<<<4096, 256, 0, stream>>>(x, xb, 4096 * 1024 / 4);
  k_trcvt<<<dim3(3072 / 64, 1024 / 64), 256, 0, stream>>>(wa, wat, 1024, 3072);
  k_trcvt<<<dim3(1024 / 64, 1024 / 64), 256, 0, stream>>>(wp, wpt, 1024, 1024);

  // qkv = x @ w_attn   (bf16 out) -- 256x192 tile, phase-interleaved
  k_gemm1<<<256, 512, 0, stream>>>(xb, wat, qkv);

  // fused causal attention -> y [4096][1024] bf16
  k_attn<<<256, 512, 0, stream>>>(qkv, yb);

  // out = y @ w_proj   (fp32 out) -- 128x128 tile, phase-interleaved
  k_gemm2<<<256, 256, 0, stream>>>(yb, wpt, out);
}